// Round 1
// baseline (343.725 us; speedup 1.0000x reference)
//
#include <hip/hip_runtime.h>
#include <math.h>

#define P 4
#define L 512
#define D 64
#define NC 4

// ws layout: s matrices, P * L * L floats = 4 MiB at offset 0.
// s is fully overwritten by compute_s before reduce_pair reads it, so the
// 0xAA re-poison of d_ws is harmless.

// Kernel 1: s[pair][j][k] = -sum_d |z0[pair][j][d] - z1[pair][k][d]|
// grid: P * (L/4) blocks (4 j-rows per block), 256 threads.
// z0 rows staged in LDS (broadcast reads); each thread streams z1 rows for
// its 2 columns and produces 4 outputs (one per j) -> 4x z1-traffic reuse.
__global__ void compute_s(const float* __restrict__ z, float* __restrict__ s_out) {
    const int bx   = blockIdx.x;
    const int pair = bx >> 7;          // / (L/4)
    const int j0   = (bx & 127) * 4;   // first of 4 rows
    const int tid  = threadIdx.x;

    __shared__ float z0s[4][D];
    // load 4 z0 rows (256 floats) coalesced
    {
        const int r = tid >> 6, d = tid & 63;
        z0s[r][d] = z[((size_t)pair * L + j0 + r) * D + d];
    }
    __syncthreads();

    const float* z1 = z + ((size_t)(P + pair) * L) * D;
    float* srow = s_out + ((size_t)pair * L + j0) * L;

    for (int k = tid; k < L; k += 256) {
        const float* z1row = z1 + (size_t)k * D;
        float acc0 = 0.f, acc1 = 0.f, acc2 = 0.f, acc3 = 0.f;
        #pragma unroll
        for (int d = 0; d < D; d += 4) {
            const float4 v = *(const float4*)(z1row + d);
            const float4 a0 = *(const float4*)(&z0s[0][d]);
            const float4 a1 = *(const float4*)(&z0s[1][d]);
            const float4 a2 = *(const float4*)(&z0s[2][d]);
            const float4 a3 = *(const float4*)(&z0s[3][d]);
            acc0 += fabsf(a0.x - v.x) + fabsf(a0.y - v.y) + fabsf(a0.z - v.z) + fabsf(a0.w - v.w);
            acc1 += fabsf(a1.x - v.x) + fabsf(a1.y - v.y) + fabsf(a1.z - v.z) + fabsf(a1.w - v.w);
            acc2 += fabsf(a2.x - v.x) + fabsf(a2.y - v.y) + fabsf(a2.z - v.z) + fabsf(a2.w - v.w);
            acc3 += fabsf(a3.x - v.x) + fabsf(a3.y - v.y) + fabsf(a3.z - v.z) + fabsf(a3.w - v.w);
        }
        srow[0 * L + k] = -acc0;   // coalesced: consecutive lanes -> consecutive k
        srow[1 * L + k] = -acc1;
        srow[2 * L + k] = -acc2;
        srow[3 * L + k] = -acc3;
    }
}

// Kernel 2: per pair -- row/col softmax stats, then sum(c*s)/sum(c), then logits.
// grid: P blocks, 1024 threads (threads 0..511 do row stats, 512..1023 col stats).
__global__ void reduce_pair(const float* __restrict__ s_in,
                            const float* __restrict__ w,
                            const float* __restrict__ bias,
                            float* __restrict__ out) {
    const int pair = blockIdx.x;
    const int tid  = threadIdx.x;
    const float* s = s_in + (size_t)pair * L * L;

    __shared__ float rowm[L], rowrcp[L], colm[L], colrcp[L];
    __shared__ float red_cs[16], red_c[16];

    if (tid < L) {
        // row stats for row r = tid (per-thread streaming reads; L2-resident)
        const int r = tid;
        const float* sr = s + (size_t)r * L;
        float m = -INFINITY;
        for (int k = 0; k < L; ++k) m = fmaxf(m, sr[k]);
        float sum = 0.f;
        for (int k = 0; k < L; ++k) sum += expf(sr[k] - m);
        rowm[r]   = m;
        rowrcp[r] = 1.0f / sum;
    } else {
        // col stats for col k = tid-512 (coalesced: consecutive lanes, consecutive cols)
        const int k = tid - L;
        float m = -INFINITY;
        for (int j = 0; j < L; ++j) m = fmaxf(m, s[(size_t)j * L + k]);
        float sum = 0.f;
        for (int j = 0; j < L; ++j) sum += expf(s[(size_t)j * L + k] - m);
        colm[k]   = m;
        colrcp[k] = 1.0f / sum;
    }
    __syncthreads();

    // accumulate c*s and c over the full 512x512 matrix
    float acc_cs = 0.f, acc_c = 0.f;
    for (int idx = tid; idx < L * L; idx += 1024) {
        const int j = idx >> 9;
        const int k = idx & (L - 1);
        const float sv = s[idx];
        const float a  = expf(sv - rowm[j]) * rowrcp[j];
        const float b  = expf(sv - colm[k]) * colrcp[k];
        const float c  = a + b - a * b;
        acc_cs += c * sv;
        acc_c  += c;
    }

    // wave (64-lane) shuffle reduce, then LDS across 16 waves
    #pragma unroll
    for (int off = 32; off > 0; off >>= 1) {
        acc_cs += __shfl_down(acc_cs, off);
        acc_c  += __shfl_down(acc_c,  off);
    }
    const int wave = tid >> 6, lane = tid & 63;
    if (lane == 0) { red_cs[wave] = acc_cs; red_c[wave] = acc_c; }
    __syncthreads();
    if (tid == 0) {
        float cs = 0.f, c = 0.f;
        #pragma unroll
        for (int v = 0; v < 16; ++v) { cs += red_cs[v]; c += red_c[v]; }
        const float c_val = cs / c;
        #pragma unroll
        for (int cls = 0; cls < NC; ++cls)
            out[pair * NC + cls] = c_val * w[cls] + bias[cls];
    }
}

extern "C" void kernel_launch(void* const* d_in, const int* in_sizes, int n_in,
                              void* d_out, int out_size, void* d_ws, size_t ws_size,
                              hipStream_t stream) {
    const float* z    = (const float*)d_in[0];   // (2P, L, D) f32
    const float* w    = (const float*)d_in[1];   // (1, NC) f32
    const float* bias = (const float*)d_in[2];   // (NC,) f32
    float* out = (float*)d_out;                  // (P, NC) f32
    float* s   = (float*)d_ws;                   // P*L*L f32 = 4 MiB scratch

    compute_s<<<dim3(P * (L / 4)), dim3(256), 0, stream>>>(z, s);
    reduce_pair<<<dim3(P), dim3(1024), 0, stream>>>(s, w, bias, out);
}

// Round 2
// 214.412 us; speedup vs baseline: 1.6031x; 1.6031x over previous
//
#include <hip/hip_runtime.h>
#include <math.h>

#define P 4
#define L 512
#define D 64
#define NC 4
#define NB3 32   // accumulate blocks per pair

// ws layout (float offsets):
//   s      : [0, P*L*L)                 = 4 MiB
//   rowm   : S_SZ        + pair*L + j
//   rowrcp : S_SZ +  2048
//   colm   : S_SZ +  4096
//   colrcp : S_SZ +  6144
//   pcs    : S_SZ +  8192  (P*NB3 = 128)
//   pc     : S_SZ +  8320
#define S_SZ   (P * L * L)
#define ROWM_O (S_SZ)
#define ROWR_O (S_SZ + 2048)
#define COLM_O (S_SZ + 4096)
#define COLR_O (S_SZ + 6144)
#define PCS_O  (S_SZ + 8192)
#define PC_O   (S_SZ + 8320)

// K1: s[pair][j][k] = -sum_d |z0[j][d]-z1[k][d]|, plus fused ROW softmax stats.
// grid P*128 blocks (4 rows each), 256 threads. Each block owns 4 complete
// rows, so row max/sumexp reduce entirely within the block.
__global__ void compute_s_rowstats(const float* __restrict__ z, float* __restrict__ ws) {
    const int bx   = blockIdx.x;
    const int pair = bx >> 7;
    const int j0   = (bx & 127) * 4;
    const int tid  = threadIdx.x;
    const int wave = tid >> 6, lane = tid & 63;

    __shared__ float z0s[4][D];
    __shared__ float wred[4][4];   // [wave][row] max partials
    __shared__ float wsum[4][4];   // [wave][row] sum partials
    {
        const int r = tid >> 6, d = tid & 63;
        z0s[r][d] = z[((size_t)pair * L + j0 + r) * D + d];
    }
    __syncthreads();

    const float* z1 = z + ((size_t)(P + pair) * L) * D;
    float* srow = ws + ((size_t)pair * L + j0) * L;

    float sv[4][2];
    #pragma unroll
    for (int i = 0; i < 2; ++i) {
        const int k = tid + i * 256;
        const float* z1row = z1 + (size_t)k * D;
        float a0 = 0.f, a1 = 0.f, a2 = 0.f, a3 = 0.f;
        #pragma unroll
        for (int d = 0; d < D; d += 4) {
            const float4 v  = *(const float4*)(z1row + d);
            const float4 b0 = *(const float4*)(&z0s[0][d]);
            const float4 b1 = *(const float4*)(&z0s[1][d]);
            const float4 b2 = *(const float4*)(&z0s[2][d]);
            const float4 b3 = *(const float4*)(&z0s[3][d]);
            a0 += fabsf(b0.x - v.x) + fabsf(b0.y - v.y) + fabsf(b0.z - v.z) + fabsf(b0.w - v.w);
            a1 += fabsf(b1.x - v.x) + fabsf(b1.y - v.y) + fabsf(b1.z - v.z) + fabsf(b1.w - v.w);
            a2 += fabsf(b2.x - v.x) + fabsf(b2.y - v.y) + fabsf(b2.z - v.z) + fabsf(b2.w - v.w);
            a3 += fabsf(b3.x - v.x) + fabsf(b3.y - v.y) + fabsf(b3.z - v.z) + fabsf(b3.w - v.w);
        }
        sv[0][i] = -a0; sv[1][i] = -a1; sv[2][i] = -a2; sv[3][i] = -a3;
        srow[0 * L + k] = -a0;
        srow[1 * L + k] = -a1;
        srow[2 * L + k] = -a2;
        srow[3 * L + k] = -a3;
    }

    // row max: butterfly across wave, then cross-wave via LDS
    float lm[4];
    #pragma unroll
    for (int r = 0; r < 4; ++r) lm[r] = fmaxf(sv[r][0], sv[r][1]);
    #pragma unroll
    for (int off = 32; off > 0; off >>= 1)
        #pragma unroll
        for (int r = 0; r < 4; ++r) lm[r] = fmaxf(lm[r], __shfl_xor(lm[r], off));
    if (lane == 0) {
        #pragma unroll
        for (int r = 0; r < 4; ++r) wred[wave][r] = lm[r];
    }
    __syncthreads();
    float rm[4];
    #pragma unroll
    for (int r = 0; r < 4; ++r)
        rm[r] = fmaxf(fmaxf(wred[0][r], wred[1][r]), fmaxf(wred[2][r], wred[3][r]));

    // row sumexp
    float ls[4];
    #pragma unroll
    for (int r = 0; r < 4; ++r) ls[r] = expf(sv[r][0] - rm[r]) + expf(sv[r][1] - rm[r]);
    #pragma unroll
    for (int off = 32; off > 0; off >>= 1)
        #pragma unroll
        for (int r = 0; r < 4; ++r) ls[r] += __shfl_xor(ls[r], off);
    if (lane == 0) {
        #pragma unroll
        for (int r = 0; r < 4; ++r) wsum[wave][r] = ls[r];
    }
    __syncthreads();
    if (tid == 0) {
        #pragma unroll
        for (int r = 0; r < 4; ++r) {
            const float rs = wsum[0][r] + wsum[1][r] + wsum[2][r] + wsum[3][r];
            ws[ROWM_O + pair * L + j0 + r] = rm[r];
            ws[ROWR_O + pair * L + j0 + r] = 1.0f / rs;
        }
    }
}

// K2: column softmax stats. grid P*8 blocks, 256 threads.
// Block owns 64 columns; wave w scans rows [w*128,(w+1)*128) coalesced.
__global__ void col_stats(float* __restrict__ ws) {
    const int pair = blockIdx.x >> 3;
    const int c0   = (blockIdx.x & 7) * 64;
    const int tid  = threadIdx.x, wave = tid >> 6, lane = tid & 63;
    const float* s = ws + (size_t)pair * L * L;
    const float* col = s + c0 + lane + (size_t)(wave * 128) * L;

    // pass 1: max (two independent chains to shorten dependency)
    float m0 = -INFINITY, m1 = -INFINITY;
    for (int jj = 0; jj < 128; jj += 2) {
        m0 = fmaxf(m0, col[(size_t)jj * L]);
        m1 = fmaxf(m1, col[(size_t)(jj + 1) * L]);
    }
    const float m = fmaxf(m0, m1);
    // pass 2: sumexp
    float s0 = 0.f, s1 = 0.f;
    for (int jj = 0; jj < 128; jj += 2) {
        s0 += expf(col[(size_t)jj * L] - m);
        s1 += expf(col[(size_t)(jj + 1) * L] - m);
    }
    const float sum = s0 + s1;

    __shared__ float wm[4][64], wsm[4][64];
    wm[wave][lane] = m; wsm[wave][lane] = sum;
    __syncthreads();
    if (tid < 64) {
        const float M = fmaxf(fmaxf(wm[0][tid], wm[1][tid]), fmaxf(wm[2][tid], wm[3][tid]));
        const float S = wsm[0][tid] * expf(wm[0][tid] - M) + wsm[1][tid] * expf(wm[1][tid] - M)
                      + wsm[2][tid] * expf(wm[2][tid] - M) + wsm[3][tid] * expf(wm[3][tid] - M);
        ws[COLM_O + pair * L + c0 + tid] = M;
        ws[COLR_O + pair * L + c0 + tid] = 1.0f / S;
    }
}

// K3: accumulate sum(c*s), sum(c). grid (NB3, P), 256 threads, 32 elem/thread.
__global__ void accumulate(float* __restrict__ ws) {
    const int pair = blockIdx.y, chunk = blockIdx.x, tid = threadIdx.x;
    const int wave = tid >> 6, lane = tid & 63;
    const float* s    = ws + (size_t)pair * L * L;
    const float* rowm = ws + ROWM_O + pair * L;
    const float* rowr = ws + ROWR_O + pair * L;
    const float* colm = ws + COLM_O + pair * L;
    const float* colr = ws + COLR_O + pair * L;

    float acc_cs = 0.f, acc_c = 0.f;
    const int base = chunk * (L * L / NB3);
    #pragma unroll 4
    for (int i = 0; i < 32; ++i) {
        const int idx = base + i * 256 + tid;
        const int j = idx >> 9, k = idx & (L - 1);
        const float sv = s[idx];
        const float a = expf(sv - rowm[j]) * rowr[j];
        const float b = expf(sv - colm[k]) * colr[k];
        const float c = a + b - a * b;
        acc_cs += c * sv;
        acc_c  += c;
    }
    #pragma unroll
    for (int off = 32; off > 0; off >>= 1) {
        acc_cs += __shfl_xor(acc_cs, off);
        acc_c  += __shfl_xor(acc_c,  off);
    }
    __shared__ float red[4][2];
    if (lane == 0) { red[wave][0] = acc_cs; red[wave][1] = acc_c; }
    __syncthreads();
    if (tid == 0) {
        ws[PCS_O + pair * NB3 + chunk] = red[0][0] + red[1][0] + red[2][0] + red[3][0];
        ws[PC_O  + pair * NB3 + chunk] = red[0][1] + red[1][1] + red[2][1] + red[3][1];
    }
}

// K4: final reduce + logits. 1 block, 128 threads (32 lanes per pair).
__global__ void finalize(const float* __restrict__ ws, const float* __restrict__ w,
                         const float* __restrict__ bias, float* __restrict__ out) {
    const int tid = threadIdx.x;
    const int pair = tid >> 5, slot = tid & 31;
    float cs = ws[PCS_O + pair * NB3 + slot];
    float c  = ws[PC_O  + pair * NB3 + slot];
    #pragma unroll
    for (int off = 16; off > 0; off >>= 1) {
        cs += __shfl_down(cs, off);
        c  += __shfl_down(c,  off);
    }
    if (slot == 0) {
        const float c_val = cs / c;
        #pragma unroll
        for (int cls = 0; cls < NC; ++cls)
            out[pair * NC + cls] = c_val * w[cls] + bias[cls];
    }
}

extern "C" void kernel_launch(void* const* d_in, const int* in_sizes, int n_in,
                              void* d_out, int out_size, void* d_ws, size_t ws_size,
                              hipStream_t stream) {
    const float* z    = (const float*)d_in[0];   // (2P, L, D) f32
    const float* w    = (const float*)d_in[1];   // (1, NC) f32
    const float* bias = (const float*)d_in[2];   // (NC,) f32
    float* out = (float*)d_out;                  // (P, NC) f32
    float* ws  = (float*)d_ws;                   // needs ~4.04 MiB

    compute_s_rowstats<<<dim3(P * (L / 4)), dim3(256), 0, stream>>>(z, ws);
    col_stats<<<dim3(P * 8), dim3(256), 0, stream>>>(ws);
    accumulate<<<dim3(NB3, P), dim3(256), 0, stream>>>(ws);
    finalize<<<dim3(1), dim3(128), 0, stream>>>(ws, w, bias, out);
}

// Round 3
// 100.489 us; speedup vs baseline: 3.4205x; 2.1337x over previous
//
#include <hip/hip_runtime.h>
#include <math.h>

#define P 4
#define L 512
#define D 64
#define NC 4
#define TK 64            // z-rows staged per LDS tile
#define NT (L / TK)      // 8 tiles
#define RS 68            // LDS row stride in floats: 272 B = 16B-aligned, spreads banks

// ws float offsets (s never materialized; ~20 KB used):
#define COLM_O 0
#define COLR_O (P * L)
#define PCS_O  (2 * P * L)             // P*128 per-block partials of sum(c*s)
#define PC_O   (2 * P * L + P * 128)   // P*128 per-block partials of sum(c)

// Stage tile t (64 rows x 64 floats) of a pair slice into rt, fully coalesced.
__device__ __forceinline__ void stage_tile(const float4* __restrict__ src4, int t,
                                           int tid, float (*rt)[RS]) {
    #pragma unroll
    for (int i = 0; i < 4; ++i) {
        const int li  = i * 256 + tid;          // tile-local float4 idx [0,1024)
        const float4 g = src4[t * (TK * D / 4) + li];
        const int row = li >> 4;
        const int c4  = li & 15;
        *(float4*)&rt[row][c4 * 4] = g;
    }
}

// L1 distance between register-cached q row and staged row kl.
__device__ __forceinline__ float dist_lane(const float4* q, const float (*rt)[RS], int kl) {
    float acc = 0.f;
    #pragma unroll
    for (int c = 0; c < 16; ++c) {
        const float4 a = q[c];
        const float4 b = *(const float4*)&rt[kl][c * 4];
        acc += fabsf(a.x - b.x) + fabsf(a.y - b.y) + fabsf(a.z - b.z) + fabsf(a.w - b.w);
    }
    return acc;
}

// K1: column softmax stats. Symmetry: col k of s(z0,z1) == row k of s(z1,z0).
// Block owns 4 k-rows (one per wave, q = z1 row), streams z0 through LDS.
// grid P*128, 256 threads.
__global__ void col_stats_k(const float* __restrict__ z, float* __restrict__ ws) {
    const int bx = blockIdx.x;
    const int pair = bx >> 7;
    const int k0 = (bx & 127) * 4;
    const int tid = threadIdx.x;
    const int wave = tid >> 6, lane = tid & 63;

    __shared__ float rt[TK][RS];

    const float* qrow = z + ((size_t)(P + pair) * L + k0 + wave) * D;  // z1 row
    float4 q[16];
    #pragma unroll
    for (int c = 0; c < 16; ++c) q[c] = ((const float4*)qrow)[c];

    const float4* src4 = (const float4*)(z + (size_t)pair * L * D);    // z0 slice

    float sv[NT];
    #pragma unroll
    for (int t = 0; t < NT; ++t) {
        __syncthreads();
        stage_tile(src4, t, tid, rt);
        __syncthreads();
        sv[t] = -dist_lane(q, rt, lane);   // s[j = t*64+lane][k = k0+wave]
    }

    // wave-local stats over the 512 j values (8 tiles x 64 lanes)
    float m = sv[0];
    #pragma unroll
    for (int t = 1; t < NT; ++t) m = fmaxf(m, sv[t]);
    #pragma unroll
    for (int off = 32; off > 0; off >>= 1) m = fmaxf(m, __shfl_xor(m, off));
    float s = 0.f;
    #pragma unroll
    for (int t = 0; t < NT; ++t) s += __expf(sv[t] - m);
    #pragma unroll
    for (int off = 32; off > 0; off >>= 1) s += __shfl_xor(s, off);
    if (lane == 0) {
        ws[COLM_O + pair * L + k0 + wave] = m;
        ws[COLR_O + pair * L + k0 + wave] = 1.0f / s;
    }
}

// K2: dist + row stats (wave-local, never stored) + c-accumulate, fused.
// Block owns 4 j-rows (one per wave, q = z0 row), streams z1 through LDS.
// grid P*128, 256 threads.
__global__ void row_acc_k(const float* __restrict__ z, float* __restrict__ ws) {
    const int bx = blockIdx.x;
    const int pair = bx >> 7;
    const int j0 = (bx & 127) * 4;
    const int tid = threadIdx.x;
    const int wave = tid >> 6, lane = tid & 63;

    __shared__ float rt[TK][RS];
    __shared__ float red[4][2];

    const float* qrow = z + ((size_t)pair * L + j0 + wave) * D;        // z0 row
    float4 q[16];
    #pragma unroll
    for (int c = 0; c < 16; ++c) q[c] = ((const float4*)qrow)[c];

    const float4* src4 = (const float4*)(z + (size_t)(P + pair) * L * D); // z1 slice

    // col stats for this lane's k per tile (coalesced)
    float cm[NT], cr[NT];
    #pragma unroll
    for (int t = 0; t < NT; ++t) {
        cm[t] = ws[COLM_O + pair * L + t * TK + lane];
        cr[t] = ws[COLR_O + pair * L + t * TK + lane];
    }

    float sv[NT];
    #pragma unroll
    for (int t = 0; t < NT; ++t) {
        __syncthreads();
        stage_tile(src4, t, tid, rt);
        __syncthreads();
        sv[t] = -dist_lane(q, rt, lane);   // s[j = j0+wave][k = t*64+lane]
    }

    // row stats, wave-local (row j0+wave)
    float m = sv[0];
    #pragma unroll
    for (int t = 1; t < NT; ++t) m = fmaxf(m, sv[t]);
    #pragma unroll
    for (int off = 32; off > 0; off >>= 1) m = fmaxf(m, __shfl_xor(m, off));
    float ssum = 0.f;
    #pragma unroll
    for (int t = 0; t < NT; ++t) ssum += __expf(sv[t] - m);
    #pragma unroll
    for (int off = 32; off > 0; off >>= 1) ssum += __shfl_xor(ssum, off);
    const float rrcp = 1.0f / ssum;

    // accumulate c*s and c
    float acc_cs = 0.f, acc_c = 0.f;
    #pragma unroll
    for (int t = 0; t < NT; ++t) {
        const float svv = sv[t];
        const float a = __expf(svv - m) * rrcp;
        const float b = __expf(svv - cm[t]) * cr[t];
        const float c = a + b - a * b;
        acc_cs += c * svv;
        acc_c  += c;
    }
    #pragma unroll
    for (int off = 32; off > 0; off >>= 1) {
        acc_cs += __shfl_xor(acc_cs, off);
        acc_c  += __shfl_xor(acc_c,  off);
    }
    if (lane == 0) { red[wave][0] = acc_cs; red[wave][1] = acc_c; }
    __syncthreads();
    if (tid == 0) {
        ws[PCS_O + pair * 128 + (bx & 127)] = red[0][0] + red[1][0] + red[2][0] + red[3][0];
        ws[PC_O  + pair * 128 + (bx & 127)] = red[0][1] + red[1][1] + red[2][1] + red[3][1];
    }
}

// K3: reduce 128 partials per pair, write logits. 1 block, 256 threads.
__global__ void finalize(const float* __restrict__ ws, const float* __restrict__ w,
                         const float* __restrict__ bias, float* __restrict__ out) {
    const int tid = threadIdx.x;
    const int pair = tid >> 6, lane = tid & 63;
    float cs = ws[PCS_O + pair * 128 + lane] + ws[PCS_O + pair * 128 + 64 + lane];
    float c  = ws[PC_O  + pair * 128 + lane] + ws[PC_O  + pair * 128 + 64 + lane];
    #pragma unroll
    for (int off = 32; off > 0; off >>= 1) {
        cs += __shfl_xor(cs, off);
        c  += __shfl_xor(c,  off);
    }
    if (lane == 0) {
        const float c_val = cs / c;
        #pragma unroll
        for (int cls = 0; cls < NC; ++cls)
            out[pair * NC + cls] = c_val * w[cls] + bias[cls];
    }
}

extern "C" void kernel_launch(void* const* d_in, const int* in_sizes, int n_in,
                              void* d_out, int out_size, void* d_ws, size_t ws_size,
                              hipStream_t stream) {
    const float* z    = (const float*)d_in[0];   // (2P, L, D) f32
    const float* w    = (const float*)d_in[1];   // (1, NC) f32
    const float* bias = (const float*)d_in[2];   // (NC,) f32
    float* out = (float*)d_out;                  // (P, NC) f32
    float* ws  = (float*)d_ws;                   // ~20 KB used

    col_stats_k<<<dim3(P * 128), dim3(256), 0, stream>>>(z, ws);
    row_acc_k  <<<dim3(P * 128), dim3(256), 0, stream>>>(z, ws);
    finalize   <<<dim3(1), dim3(256), 0, stream>>>(ws, w, bias, out);
}